// Round 17
// baseline (102.209 us; speedup 1.0000x reference)
//
#include <hip/hip_runtime.h>
#include <hip/hip_bf16.h>
#include <math.h>

// ---------------------------------------------------------------------------
// KAN-Conv CIFAR net on gfx950, round 22.
// r21 = 98.9us. Ledger: ~68us fixed (40 ws-poison fill + 28 graph/replay --
// r17 proved the 28 is launch-count-independent), kernels ~31us.
// This round: producer-side records.
//  (1) Kernel A writes h1 as FINISHED bf16 act-records (grec, uint4/px):
//      the pooled f32 values are already in A's registers, and A has 2
//      blocks/image + idle oc>=8 lanes. B's act2 staging becomes zrec
//      prefill + coalesced 16B copy (zero VALU). Bit-identical records.
//  (2) A also preps fused w2 (w2g, prep range 5760, blocks 0..11): B loses
//      the w2-fuse phase + a barrier; B LDS 59.9 -> 40.5KB.
//  (3) B preloads bfr2+bfr3 from w2g/w3g EARLY (before first barrier): L2
//      latency hides under prefill/copy; ~110 VGPR held, cap 256.
// MFMA bodies / pooling / linear: r21-verbatim.
// ---------------------------------------------------------------------------

#define BATCH 256

typedef short bf16x8 __attribute__((ext_vector_type(8)));
typedef float f32x4  __attribute__((ext_vector_type(4)));

__device__ __forceinline__ unsigned pk2(float a, float b) {
    __hip_bfloat162 h = __float22bfloat162_rn(make_float2(a, b));
    unsigned u;
    __builtin_memcpy(&u, &h, 4);
    return u;
}
__device__ __forceinline__ unsigned f2bf(float f) {
    __hip_bfloat16 h = __float2bfloat16(f);
    unsigned short us;
    __builtin_memcpy(&us, &h, 2);
    return (unsigned)us;
}

// Closed-form cubic B-spline on the uniform extended grid g[i]=(i-3)*(2/3)-1.
__device__ __forceinline__ void bspline_basis(float x, float bs[6]) {
    float s  = (x + 3.0f) * 1.5f;
    float cf = floorf(s);
    float t  = s - cf;
    int  ci  = (int)cf;
    float t2 = t * t, t3 = t2 * t;
    float omt = 1.0f - t;
    const float k6 = 1.0f / 6.0f;
    float w0 = omt * omt * omt * k6;
    float w1 = (3.0f * t3 - 6.0f * t2 + 4.0f) * k6;
    float w2 = (-3.0f * t3 + 3.0f * t2 + 3.0f * t + 1.0f) * k6;
    float w3 = t3 * k6;
#pragma unroll
    for (int i = 0; i < 6; ++i) {
        int j = i - ci + 3;                // which of the 4 weights lands here
        float v = 0.0f;
        v = (j == 0) ? w0 : v;
        v = (j == 1) ? w1 : v;
        v = (j == 2) ? w2 : v;
        v = (j == 3) ? w3 : v;
        bs[i] = v;
    }
}

// [silu, b0..b5, 0] as 8 bf16 in one uint4.
__device__ __forceinline__ uint4 act_record(float val) {
    float silu = __fdividef(val, 1.0f + __expf(-val));
    float bs[6];
    bspline_basis(val, bs);
    uint4 r;
    r.x = pk2(silu, bs[0]);
    r.y = pk2(bs[1], bs[2]);
    r.z = pk2(bs[3], bs[4]);
    r.w = f2bf(bs[5]);
    return r;
}

__device__ __forceinline__ uint4 fuse_w(const float* bw, const float* sw,
                                        const float* sc, int j) {
    float s = sc[j];
    uint4 r;
    r.x = pk2(bw[j],             sw[j * 6 + 0] * s);
    r.y = pk2(sw[j * 6 + 1] * s, sw[j * 6 + 2] * s);
    r.z = pk2(sw[j * 6 + 3] * s, sw[j * 6 + 4] * s);
    r.w = f2bf(sw[j * 6 + 5] * s);
    return r;
}

// ---------------------------------------------------------------------------
// Kernel A: L1 conv+pool -> grec (bf16 act-records) + prep of w2g/w3g.
// grid 512 (img x vhalf) x 512 threads, 2 blocks/CU.
// ---------------------------------------------------------------------------
__global__ __launch_bounds__(512, 4) void kan_l1(
        const float* __restrict__ x,
        const float* __restrict__ bw, const float* __restrict__ sw,
        const float* __restrict__ sc,
        const float* __restrict__ bw2, const float* __restrict__ sw2,
        const float* __restrict__ sc2,
        const float* __restrict__ bw3, const float* __restrict__ sw3,
        const float* __restrict__ sc3,
        uint4* __restrict__ w2g, uint4* __restrict__ w3g,
        uint4* __restrict__ grec) {
    constexpr int C = 3, F = 27, FP = 28, NS = 7;
    constexpr int RT = 18, TC = 34, NT = 512;

    __shared__ uint4 s_act[C * RT * TC];           // 1836 recs = 29.4KB
    __shared__ uint4 s_w[FP * 16];                 // 7.2KB

    const int tid = threadIdx.x;
    const int bid = blockIdx.x;
    const int b   = bid >> 1;
    const int v   = bid & 1;

    // ---- prep w2g (entries 0..1151) + w3g (1152..5759), blocks 0..11
    if (bid < 12) {
        int i = bid * NT + tid;
        if (i < 5760) {
            if (i < 1152) {
                int o = i / 72, fp = i % 72;
                w2g[fp * 16 + o] = fuse_w(bw2, sw2, sc2, i);
            } else {
                int j = i - 1152;
                int o = j / 144, fp = j % 144;
                w3g[fp * 32 + o] = fuse_w(bw3, sw3, sc3, j);
            }
        }
    }

    // ---- stage own weights [fp][16] (zeros for pad tap / o>=8)
    for (int i = tid; i < FP * 16; i += NT) {
        int fp = i >> 4, o = i & 15;
        uint4 r = make_uint4(0u, 0u, 0u, 0u);
        if (fp < F && o < 8) r = fuse_w(bw, sw, sc, o * F + fp);
        s_w[i] = r;
    }

    // ---- stage acts: zrec prefill, then interior-only (17 rows x 32 cols/ch)
    const uint4 zrec = act_record(0.0f);
    for (int i = tid; i < C * RT * TC; i += NT) s_act[i] = zrec;
    __syncthreads();
    const float* xb = x + (size_t)b * C * 32 * 32;
    if (tid < 408) {                       // 3ch x 17 rows x 8 float4s
        int cc  = tid / 136;
        int rem = tid - cc * 136;
        int rr_i = rem >> 3;
        int c4   = (rem & 7) * 4;
        float4 v4 = *(const float4*)&xb[(cc * 32 + rr_i + 15 * v) * 32 + c4];
        uint4* dst = &s_act[(cc * RT + rr_i + 1 - v) * TC + c4 + 1];
        dst[0] = act_record(v4.x);
        dst[1] = act_record(v4.y);
        dst[2] = act_record(v4.z);
        dst[3] = act_record(v4.w);
    }
    __syncthreads();

    const int lane = tid & 63;
    const int wv   = tid >> 6;
    const int kg   = lane >> 4;
    const int oc   = lane & 15;
    const int m    = lane & 15;

    bf16x8 bfr[NS];
#pragma unroll
    for (int s = 0; s < NS; ++s)
        bfr[s] = *reinterpret_cast<const bf16x8*>(&s_w[(4 * s + kg) * 16 + oc]);

    int pixoff[4];
#pragma unroll
    for (int t = 0; t < 4; ++t)
        pixoff[t] = (2 * wv + (t >> 1)) * TC + 16 * (t & 1) + m;

    f32x4 acc[4];
#pragma unroll
    for (int t = 0; t < 4; ++t) acc[t] = (f32x4){0.f, 0.f, 0.f, 0.f};

#pragma unroll
    for (int s = 0; s < NS; ++s) {
        int tp = 4 * s + kg;
        tp = (tp > F - 1) ? F - 1 : tp;            // pad tap: B=0 anyway
        int c  = tp / 9;
        int t9 = tp - 9 * c;
        int ky = t9 / 3;
        int kx = t9 - 3 * ky;
        int base = (c * RT + ky) * TC + kx;
#pragma unroll
        for (int t = 0; t < 4; ++t) {
            bf16x8 a = *reinterpret_cast<const bf16x8*>(&s_act[base + pixoff[t]]);
            acc[t] = __builtin_amdgcn_mfma_f32_16x16x32_bf16(a, bfr[s], acc[t], 0, 0, 0);
        }
    }

    // ---- pool + producer-side record conversion -> grec
    if (oc < 8) {
        f32x4 e0, e1;
#pragma unroll
        for (int p = 0; p < 4; ++p) {
            e0[p] = fmaxf(acc[0][p], acc[2][p]);
            e1[p] = fmaxf(acc[1][p], acc[3][p]);
        }
        uint4* op = grec + (((size_t)b * 8 + oc) * 16 + (8 * v + wv)) * 16;
        op[2 * kg]         = act_record(fmaxf(e0[0], e0[1]));
        op[2 * kg + 1]     = act_record(fmaxf(e0[2], e0[3]));
        op[8 + 2 * kg]     = act_record(fmaxf(e1[0], e1[1]));
        op[8 + 2 * kg + 1] = act_record(fmaxf(e1[2], e1[3]));
    }
}

// ---------------------------------------------------------------------------
// Kernel B: L2 conv+pool -> L3 conv+pool -> linear, one block per image.
// grid 256 x 512 threads.  LDS arena (41472 B):
//   P1: act2[2592]u4 (0..41471)
//   P2: h2[1024]f (0..4095) | act3[1600]u4 (4096..29695)
//   P3: h3[512]f (0..2047)
// w2/w3 fragments live in REGISTERS (preloaded early from w2g/w3g).
// ---------------------------------------------------------------------------
__global__ __launch_bounds__(512, 2) void kan_l2l3lin(
        const uint4* __restrict__ grec,
        const uint4* __restrict__ w2g,
        const uint4* __restrict__ w3g,
        const float* __restrict__ lin_w, const float* __restrict__ lin_b,
        float* __restrict__ out) {
    constexpr int NT = 512;
    __shared__ alignas(16) unsigned char s_mem[41472];
    uint4* s_act2 = (uint4*)s_mem;                 // [2592]
    float* s_h2   = (float*)s_mem;                 // [1024]
    uint4* s_act3 = (uint4*)(s_mem + 4096);        // [1600]
    float* s_h3   = (float*)s_mem;                 // [512]

    const int tid = threadIdx.x;
    const int n   = blockIdx.x;
    const int lane = tid & 63;
    const int wv   = tid >> 6;
    const int kg   = lane >> 4;
    const int oc   = lane & 15;
    const int m    = lane & 15;

    const uint4 zrec = act_record(0.0f);

    // ---- early weight-fragment preloads (global, hide under staging)
    bf16x8 bfr2[18];
#pragma unroll
    for (int s = 0; s < 18; ++s)
        bfr2[s] = *reinterpret_cast<const bf16x8*>(&w2g[(4 * s + kg) * 16 + oc]);
    const int o03 = 16 * (wv >> 2);
    bf16x8 bfr3[36];
#pragma unroll
    for (int s = 0; s < 36; ++s)
        bfr3[s] = *reinterpret_cast<const bf16x8*>(&w3g[(4 * s + kg) * 32 + o03 + oc]);

    // ---- P1: act2 zrec prefill, then interior COPY from grec (no VALU)
    for (int i = tid; i < 2592; i += NT) s_act2[i] = zrec;
    __syncthreads();
    {
        const uint4* grn = grec + (size_t)n * 2048;
#pragma unroll
        for (int k = 0; k < 4; ++k) {
            int i = tid + k * NT;
            uint4 r = grn[i];
            int cc = i >> 8, rr_i = (i >> 4) & 15, col = i & 15;
            s_act2[(cc * 18 + rr_i + 1) * 18 + col + 1] = r;
        }
    }
    __syncthreads();

    // ---- L2 MFMA (K split 9+9 for ILP): 2 row-tiles per wave
    {
        const int p0 = (2 * wv) * 18 + m;
        const int p1 = p0 + 18;
        f32x4 a0 = (f32x4){0.f, 0.f, 0.f, 0.f}, a1 = a0, b0 = a0, b1 = a0;
#pragma unroll
        for (int s = 0; s < 18; ++s) {
            int tp = 4 * s + kg;
            int c  = tp / 9;
            int t9 = tp - 9 * c;
            int ky = t9 / 3;
            int kx = t9 - 3 * ky;
            int base = (c * 18 + ky) * 18 + kx;
            bf16x8 av0 = *reinterpret_cast<const bf16x8*>(&s_act2[base + p0]);
            bf16x8 av1 = *reinterpret_cast<const bf16x8*>(&s_act2[base + p1]);
            if (s < 9) {
                a0 = __builtin_amdgcn_mfma_f32_16x16x32_bf16(av0, bfr2[s], a0, 0, 0, 0);
                a1 = __builtin_amdgcn_mfma_f32_16x16x32_bf16(av1, bfr2[s], a1, 0, 0, 0);
            } else {
                b0 = __builtin_amdgcn_mfma_f32_16x16x32_bf16(av0, bfr2[s], b0, 0, 0, 0);
                b1 = __builtin_amdgcn_mfma_f32_16x16x32_bf16(av1, bfr2[s], b1, 0, 0, 0);
            }
        }
        a0 = a0 + b0;
        a1 = a1 + b1;
        float e0 = fmaxf(a0[0], a1[0]);
        float e1 = fmaxf(a0[1], a1[1]);
        float e2 = fmaxf(a0[2], a1[2]);
        float e3 = fmaxf(a0[3], a1[3]);
        __syncthreads();                           // act2 reads done
        // pooled h2: ch=oc, prow=wv, pcols 2kg,2kg+1
        s_h2[(oc * 8 + wv) * 8 + 2 * kg]     = fmaxf(e0, e1);
        s_h2[(oc * 8 + wv) * 8 + 2 * kg + 1] = fmaxf(e2, e3);
    }
    __syncthreads();                               // h2 visible

    // ---- P2 stage: act3 zrec prefill, then interior (16ch x 8 x 8)
    for (int i = tid; i < 1600; i += NT) s_act3[i] = zrec;
    __syncthreads();
    for (int i = tid; i < 1024; i += NT) {
        float val = s_h2[i];
        int cc   = i >> 6;
        int rr_i = (i >> 3) & 7;
        int col_i = i & 7;
        s_act3[(cc * 10 + rr_i + 1) * 10 + col_i + 1] = act_record(val);
    }
    __syncthreads();

    // ---- L3 MFMA (K split 18+18): wave wv -> mt=wv&3, o-half 16*(wv>>2)
    {
        const int mt  = wv & 3;
        const int poff = (2 * mt + (m >> 3)) * 10 + (m & 7);
        f32x4 a3 = (f32x4){0.f, 0.f, 0.f, 0.f}, a3b = a3;
#pragma unroll
        for (int s = 0; s < 36; ++s) {
            int tp = 4 * s + kg;
            int c  = tp / 9;
            int t9 = tp - 9 * c;
            int ky = t9 / 3;
            int kx = t9 - 3 * ky;
            int base = (c * 10 + ky) * 10 + kx;
            bf16x8 av = *reinterpret_cast<const bf16x8*>(&s_act3[base + poff]);
            if (s < 18)
                a3 = __builtin_amdgcn_mfma_f32_16x16x32_bf16(av, bfr3[s], a3, 0, 0, 0);
            else
                a3b = __builtin_amdgcn_mfma_f32_16x16x32_bf16(av, bfr3[s], a3b, 0, 0, 0);
        }
        a3 = a3 + a3b;
        float q0 = fmaxf(a3[0], a3[1]);
        float q1 = fmaxf(a3[2], a3[3]);
        float y0 = fmaxf(q0, __shfl_xor(q0, 32));
        float y1 = fmaxf(q1, __shfl_xor(q1, 32));
        // h3 (bytes 0..2047) disjoint from act3 (4096+): no pre-sync needed
        if (kg < 2) {
            s_h3[(o03 + oc) * 16 + mt * 4 + 2 * kg]     = y0;
            s_h3[(o03 + oc) * 16 + mt * 4 + 2 * kg + 1] = y1;
        }
    }
    __syncthreads();

    // ---- linear: 2-deep pipelined w-row loads + shfl reduce
    {
        const float4* hf = (const float4*)s_h3;
        const float4 h0v = hf[lane];
        const float4 h1v = hf[lane + 64];
        const float4* wr = (const float4*)(lin_w + (size_t)wv * 512);
        float4 w0 = wr[lane];
        float4 w1 = wr[lane + 64];
#pragma unroll 1
        for (int o = wv; o < 100; o += 8) {
            float4 nw0, nw1;
            const int on = o + 8;
            if (on < 100) {
                const float4* wn = (const float4*)(lin_w + (size_t)on * 512);
                nw0 = wn[lane];
                nw1 = wn[lane + 64];
            }
            float p = w0.x * h0v.x + w0.y * h0v.y + w0.z * h0v.z + w0.w * h0v.w
                    + w1.x * h1v.x + w1.y * h1v.y + w1.z * h1v.z + w1.w * h1v.w;
            p += __shfl_xor(p, 32);
            p += __shfl_xor(p, 16);
            p += __shfl_xor(p, 8);
            p += __shfl_xor(p, 4);
            p += __shfl_xor(p, 2);
            p += __shfl_xor(p, 1);
            if (lane == 0) out[(size_t)n * 100 + o] = p + lin_b[o];
            w0 = nw0;
            w1 = nw1;
        }
    }
}

extern "C" void kernel_launch(void* const* d_in, const int* in_sizes, int n_in,
                              void* d_out, int out_size, void* d_ws, size_t ws_size,
                              hipStream_t stream) {
    const float* x     = (const float*)d_in[0];
    const float* c1_bw = (const float*)d_in[1];
    const float* c1_sw = (const float*)d_in[2];
    const float* c1_sc = (const float*)d_in[3];
    const float* c2_bw = (const float*)d_in[4];
    const float* c2_sw = (const float*)d_in[5];
    const float* c2_sc = (const float*)d_in[6];
    const float* c3_bw = (const float*)d_in[7];
    const float* c3_sw = (const float*)d_in[8];
    const float* c3_sc = (const float*)d_in[9];
    const float* lin_w = (const float*)d_in[10];
    const float* lin_b = (const float*)d_in[11];
    float* out = (float*)d_out;

    uint4* grec = (uint4*)d_ws;          // 256 imgs x 2048 records = 8 MB
    uint4* w2g  = grec + 524288;         // 1152 records
    uint4* w3g  = w2g + 1152;            // 4608 records

    // Kernel A: L1 -> grec (bf16 act-records); + w2g/w3g prep (blocks 0-11).
    kan_l1<<<512, 512, 0, stream>>>(x, c1_bw, c1_sw, c1_sc,
                                    c2_bw, c2_sw, c2_sc,
                                    c3_bw, c3_sw, c3_sc, w2g, w3g, grec);
    // Kernel B: per-image L2 -> L3 -> linear. 256 blocks x 512.
    kan_l2l3lin<<<256, 512, 0, stream>>>(grec, w2g, w3g, lin_w, lin_b, out);
}

// Round 19
// 98.324 us; speedup vs baseline: 1.0395x; 1.0395x over previous
//
#include <hip/hip_runtime.h>
#include <hip/hip_bf16.h>
#include <math.h>

// ---------------------------------------------------------------------------
// KAN-Conv CIFAR net on gfx950, round 24.
// r23 failed (absmax 3e36): act2 halo used `if (tid < 544)` with NT=512 ->
// threads 512..543 don't exist -> 32 halo positions of channel 7 never
// written -> uninitialized LDS into L2 MFMA. Fix: grid-stride loop
// (i = tid; i < 544; i += NT). act3 halo normalized to same form.
// Everything else r23-identical (= r21 base + halo-only prefill, which
// removes one __syncthreads + dead zrec stores from each staging phase).
// Coverage proofs (re-verified): act1 halo 68/ch = 34 (halo row) + 17x2
// (side cols); act2 68/ch = 36 (rows 0,17) + 16x2; act3 36/ch = 20 (rows
// 0,9) + 8x2; each position exactly once; union == tile minus interior.
// ---------------------------------------------------------------------------

#define BATCH 256

typedef short bf16x8 __attribute__((ext_vector_type(8)));
typedef float f32x4  __attribute__((ext_vector_type(4)));

__device__ __forceinline__ unsigned pk2(float a, float b) {
    __hip_bfloat162 h = __float22bfloat162_rn(make_float2(a, b));
    unsigned u;
    __builtin_memcpy(&u, &h, 4);
    return u;
}
__device__ __forceinline__ unsigned f2bf(float f) {
    __hip_bfloat16 h = __float2bfloat16(f);
    unsigned short us;
    __builtin_memcpy(&us, &h, 2);
    return (unsigned)us;
}

// Closed-form cubic B-spline on the uniform extended grid g[i]=(i-3)*(2/3)-1.
__device__ __forceinline__ void bspline_basis(float x, float bs[6]) {
    float s  = (x + 3.0f) * 1.5f;
    float cf = floorf(s);
    float t  = s - cf;
    int  ci  = (int)cf;
    float t2 = t * t, t3 = t2 * t;
    float omt = 1.0f - t;
    const float k6 = 1.0f / 6.0f;
    float w0 = omt * omt * omt * k6;
    float w1 = (3.0f * t3 - 6.0f * t2 + 4.0f) * k6;
    float w2 = (-3.0f * t3 + 3.0f * t2 + 3.0f * t + 1.0f) * k6;
    float w3 = t3 * k6;
#pragma unroll
    for (int i = 0; i < 6; ++i) {
        int j = i - ci + 3;                // which of the 4 weights lands here
        float v = 0.0f;
        v = (j == 0) ? w0 : v;
        v = (j == 1) ? w1 : v;
        v = (j == 2) ? w2 : v;
        v = (j == 3) ? w3 : v;
        bs[i] = v;
    }
}

// [silu, b0..b5, 0] as 8 bf16 in one uint4.
__device__ __forceinline__ uint4 act_record(float val) {
    float silu = __fdividef(val, 1.0f + __expf(-val));
    float bs[6];
    bspline_basis(val, bs);
    uint4 r;
    r.x = pk2(silu, bs[0]);
    r.y = pk2(bs[1], bs[2]);
    r.z = pk2(bs[3], bs[4]);
    r.w = f2bf(bs[5]);
    return r;
}

__device__ __forceinline__ uint4 fuse_w(const float* bw, const float* sw,
                                        const float* sc, int j) {
    float s = sc[j];
    uint4 r;
    r.x = pk2(bw[j],             sw[j * 6 + 0] * s);
    r.y = pk2(sw[j * 6 + 1] * s, sw[j * 6 + 2] * s);
    r.z = pk2(sw[j * 6 + 3] * s, sw[j * 6 + 4] * s);
    r.w = f2bf(sw[j * 6 + 5] * s);
    return r;
}

// ---------------------------------------------------------------------------
// Kernel A: L1 conv+pool + prep of L3 bf16 weight table w3g.
// grid 512 (img x vhalf) x 512 threads, 2 blocks/CU.
// ---------------------------------------------------------------------------
__global__ __launch_bounds__(512, 4) void kan_l1(
        const float* __restrict__ x,
        const float* __restrict__ bw, const float* __restrict__ sw,
        const float* __restrict__ sc,
        const float* __restrict__ bw3, const float* __restrict__ sw3,
        const float* __restrict__ sc3,
        uint4* __restrict__ w3g,
        float* __restrict__ out) {
    constexpr int C = 3, F = 27, FP = 28, NS = 7;
    constexpr int RT = 18, TC = 34, NT = 512;

    __shared__ uint4 s_act[C * RT * TC];           // 1836 recs = 29.4KB
    __shared__ uint4 s_w[FP * 16];                 // 7.2KB

    const int tid = threadIdx.x;
    const int bid = blockIdx.x;
    const int b   = bid >> 1;
    const int v   = bid & 1;

    // ---- prep w3g (blocks 0..8): [tap][32] bf16x8
    if (bid < 9) {
        int i = bid * NT + tid;
        if (i < 4608) {
            int o = i / 144, fp = i % 144;
            w3g[fp * 32 + o] = fuse_w(bw3, sw3, sc3, i);
        }
    }

    // ---- stage own weights [fp][16] (zeros for pad tap / o>=8)
    for (int i = tid; i < FP * 16; i += NT) {
        int fp = i >> 4, o = i & 15;
        uint4 r = make_uint4(0u, 0u, 0u, 0u);
        if (fp < F && o < 8) r = fuse_w(bw, sw, sc, o * F + fp);
        s_w[i] = r;
    }

    // ---- stage acts: halo-only zrec + interior, one phase (disjoint writes)
    const uint4 zrec = act_record(0.0f);
    if (tid < 204) {                       // 3ch x 68 halo positions
        int cc = tid / 68, r = tid % 68;
        int idx;
        if (r < 34) idx = (cc * RT + 17 * v) * TC + r;             // halo row
        else {
            int k = r - 34;                // 17 written rows x cols {0,33}
            idx = (cc * RT + (1 - v) + (k >> 1)) * TC + ((k & 1) ? 33 : 0);
        }
        s_act[idx] = zrec;
    }
    const float* xb = x + (size_t)b * C * 32 * 32;
    if (tid < 408) {                       // 3ch x 17 rows x 8 float4s
        int cc  = tid / 136;
        int rem = tid - cc * 136;
        int rr_i = rem >> 3;
        int c4   = (rem & 7) * 4;
        float4 v4 = *(const float4*)&xb[(cc * 32 + rr_i + 15 * v) * 32 + c4];
        uint4* dst = &s_act[(cc * RT + rr_i + 1 - v) * TC + c4 + 1];
        dst[0] = act_record(v4.x);
        dst[1] = act_record(v4.y);
        dst[2] = act_record(v4.z);
        dst[3] = act_record(v4.w);
    }
    __syncthreads();

    const int lane = tid & 63;
    const int wv   = tid >> 6;
    const int kg   = lane >> 4;
    const int oc   = lane & 15;
    const int m    = lane & 15;

    bf16x8 bfr[NS];
#pragma unroll
    for (int s = 0; s < NS; ++s)
        bfr[s] = *reinterpret_cast<const bf16x8*>(&s_w[(4 * s + kg) * 16 + oc]);

    int pixoff[4];
#pragma unroll
    for (int t = 0; t < 4; ++t)
        pixoff[t] = (2 * wv + (t >> 1)) * TC + 16 * (t & 1) + m;

    f32x4 acc[4];
#pragma unroll
    for (int t = 0; t < 4; ++t) acc[t] = (f32x4){0.f, 0.f, 0.f, 0.f};

#pragma unroll
    for (int s = 0; s < NS; ++s) {
        int tp = 4 * s + kg;
        tp = (tp > F - 1) ? F - 1 : tp;            // pad tap: B=0 anyway
        int c  = tp / 9;
        int t9 = tp - 9 * c;
        int ky = t9 / 3;
        int kx = t9 - 3 * ky;
        int base = (c * RT + ky) * TC + kx;
#pragma unroll
        for (int t = 0; t < 4; ++t) {
            bf16x8 a = *reinterpret_cast<const bf16x8*>(&s_act[base + pixoff[t]]);
            acc[t] = __builtin_amdgcn_mfma_f32_16x16x32_bf16(a, bfr[s], acc[t], 0, 0, 0);
        }
    }

    if (oc < 8) {
        f32x4 e0, e1;
#pragma unroll
        for (int p = 0; p < 4; ++p) {
            e0[p] = fmaxf(acc[0][p], acc[2][p]);
            e1[p] = fmaxf(acc[1][p], acc[3][p]);
        }
        float* op = out + (((size_t)b * 8 + oc) * 16 + (8 * v + wv)) * 16;
        op[2 * kg]         = fmaxf(e0[0], e0[1]);
        op[2 * kg + 1]     = fmaxf(e0[2], e0[3]);
        op[8 + 2 * kg]     = fmaxf(e1[0], e1[1]);
        op[8 + 2 * kg + 1] = fmaxf(e1[2], e1[3]);
    }
}

// ---------------------------------------------------------------------------
// Kernel B: L2 conv+pool -> L3 conv+pool -> linear, one block per image.
// grid 256 x 512 threads.  LDS arena phases:
//   P1: act2[2592]u4 (0..41471) | w2[1152]u4 (41472..59903)
//   P2: h2[1024]f   (0..4095)   | act3[1600]u4 (4096..29695)
//   P3: h3[512]f    (0..2047)
// ---------------------------------------------------------------------------
__global__ __launch_bounds__(512, 2) void kan_l2l3lin(
        const float* __restrict__ h1,
        const float* __restrict__ bw2, const float* __restrict__ sw2,
        const float* __restrict__ sc2,
        const uint4* __restrict__ w3g,
        const float* __restrict__ lin_w, const float* __restrict__ lin_b,
        float* __restrict__ out) {
    constexpr int NT = 512;
    __shared__ alignas(16) unsigned char s_mem[59904];
    uint4* s_act2 = (uint4*)s_mem;                 // [2592]
    uint4* s_w2   = (uint4*)(s_mem + 41472);       // [1152]
    float* s_h2   = (float*)s_mem;                 // [1024]
    uint4* s_act3 = (uint4*)(s_mem + 4096);        // [1600]
    float* s_h3   = (float*)s_mem;                 // [512]

    const int tid = threadIdx.x;
    const int n   = blockIdx.x;
    const int lane = tid & 63;
    const int wv   = tid >> 6;
    const int kg   = lane >> 4;
    const int oc   = lane & 15;
    const int m    = lane & 15;

    const uint4 zrec = act_record(0.0f);

    // ---- P1 stage (one phase, disjoint writes): w2 fuse + act2 halo + int.
    for (int i = tid; i < 72 * 16; i += NT) {
        int fp = i >> 4, o = i & 15;
        s_w2[i] = fuse_w(bw2, sw2, sc2, o * 72 + fp);
    }
    for (int i = tid; i < 544; i += NT) {  // 8ch x 68 halo positions (18x18)
        int cc = i / 68, r = i % 68;       // (r23 BUG: `if (tid<544)` with
        int idx;                           //  NT=512 left 32 slots unwritten)
        if (r < 36) idx = (cc * 18 + ((r < 18) ? 0 : 17)) * 18 + (r % 18);
        else {
            int k = r - 36;                // rows 1..16 x cols {0,17}
            idx = (cc * 18 + 1 + (k >> 1)) * 18 + ((k & 1) ? 17 : 0);
        }
        s_act2[idx] = zrec;
    }
    {
        const float4* xb4 = (const float4*)(h1 + (size_t)n * 8 * 16 * 16);
        float4 v4 = xb4[tid];                      // 2048 floats = 512 float4
        int cc   = tid >> 6;
        int rr_i = (tid >> 2) & 15;
        int c4   = (tid & 3) * 4;
        uint4* dst = &s_act2[(cc * 18 + rr_i + 1) * 18 + c4 + 1];
        dst[0] = act_record(v4.x);
        dst[1] = act_record(v4.y);
        dst[2] = act_record(v4.z);
        dst[3] = act_record(v4.w);
    }
    __syncthreads();

    // ---- L2 MFMA (K split 9+9 for ILP): 2 row-tiles per wave
    {
        bf16x8 bfr2[18];
#pragma unroll
        for (int s = 0; s < 18; ++s)
            bfr2[s] = *reinterpret_cast<const bf16x8*>(&s_w2[(4 * s + kg) * 16 + oc]);
        const int p0 = (2 * wv) * 18 + m;
        const int p1 = p0 + 18;
        f32x4 a0 = (f32x4){0.f, 0.f, 0.f, 0.f}, a1 = a0, b0 = a0, b1 = a0;
#pragma unroll
        for (int s = 0; s < 18; ++s) {
            int tp = 4 * s + kg;
            int c  = tp / 9;
            int t9 = tp - 9 * c;
            int ky = t9 / 3;
            int kx = t9 - 3 * ky;
            int base = (c * 18 + ky) * 18 + kx;
            bf16x8 av0 = *reinterpret_cast<const bf16x8*>(&s_act2[base + p0]);
            bf16x8 av1 = *reinterpret_cast<const bf16x8*>(&s_act2[base + p1]);
            if (s < 9) {
                a0 = __builtin_amdgcn_mfma_f32_16x16x32_bf16(av0, bfr2[s], a0, 0, 0, 0);
                a1 = __builtin_amdgcn_mfma_f32_16x16x32_bf16(av1, bfr2[s], a1, 0, 0, 0);
            } else {
                b0 = __builtin_amdgcn_mfma_f32_16x16x32_bf16(av0, bfr2[s], b0, 0, 0, 0);
                b1 = __builtin_amdgcn_mfma_f32_16x16x32_bf16(av1, bfr2[s], b1, 0, 0, 0);
            }
        }
        a0 = a0 + b0;
        a1 = a1 + b1;
        float e0 = fmaxf(a0[0], a1[0]);
        float e1 = fmaxf(a0[1], a1[1]);
        float e2 = fmaxf(a0[2], a1[2]);
        float e3 = fmaxf(a0[3], a1[3]);
        __syncthreads();                           // act2/w2 reads done
        // pooled h2: ch=oc, prow=wv, pcols 2kg,2kg+1
        s_h2[(oc * 8 + wv) * 8 + 2 * kg]     = fmaxf(e0, e1);
        s_h2[(oc * 8 + wv) * 8 + 2 * kg + 1] = fmaxf(e2, e3);
    }
    __syncthreads();                               // h2 visible

    // ---- P2 stage (one phase, disjoint writes): act3 halo + interior
    for (int i = tid; i < 576; i += NT) {  // 16ch x 36 halo positions (10x10)
        int cc = i / 36, r = i % 36;
        int idx;
        if (r < 20) idx = (cc * 10 + ((r < 10) ? 0 : 9)) * 10 + (r % 10);
        else {
            int k = r - 20;                // rows 1..8 x cols {0,9}
            idx = (cc * 10 + 1 + (k >> 1)) * 10 + ((k & 1) ? 9 : 0);
        }
        s_act3[idx] = zrec;
    }
    for (int i = tid; i < 1024; i += NT) {
        float val = s_h2[i];
        int cc   = i >> 6;
        int rr_i = (i >> 3) & 7;
        int col_i = i & 7;
        s_act3[(cc * 10 + rr_i + 1) * 10 + col_i + 1] = act_record(val);
    }
    __syncthreads();

    // ---- L3 MFMA (K split 18+18): wave wv -> mt=wv&3, o-half 16*(wv>>2)
    {
        const int mt  = wv & 3;
        const int o03 = 16 * (wv >> 2);
        bf16x8 bfr3[36];
#pragma unroll
        for (int s = 0; s < 36; ++s)
            bfr3[s] = *reinterpret_cast<const bf16x8*>(&w3g[(4 * s + kg) * 32 + o03 + oc]);
        const int poff = (2 * mt + (m >> 3)) * 10 + (m & 7);
        f32x4 a3 = (f32x4){0.f, 0.f, 0.f, 0.f}, a3b = a3;
#pragma unroll
        for (int s = 0; s < 36; ++s) {
            int tp = 4 * s + kg;
            int c  = tp / 9;
            int t9 = tp - 9 * c;
            int ky = t9 / 3;
            int kx = t9 - 3 * ky;
            int base = (c * 10 + ky) * 10 + kx;
            bf16x8 av = *reinterpret_cast<const bf16x8*>(&s_act3[base + poff]);
            if (s < 18)
                a3 = __builtin_amdgcn_mfma_f32_16x16x32_bf16(av, bfr3[s], a3, 0, 0, 0);
            else
                a3b = __builtin_amdgcn_mfma_f32_16x16x32_bf16(av, bfr3[s], a3b, 0, 0, 0);
        }
        a3 = a3 + a3b;
        float q0 = fmaxf(a3[0], a3[1]);
        float q1 = fmaxf(a3[2], a3[3]);
        float y0 = fmaxf(q0, __shfl_xor(q0, 32));
        float y1 = fmaxf(q1, __shfl_xor(q1, 32));
        // h3 (bytes 0..2047) disjoint from act3 (4096+): no pre-sync needed
        if (kg < 2) {
            s_h3[(o03 + oc) * 16 + mt * 4 + 2 * kg]     = y0;
            s_h3[(o03 + oc) * 16 + mt * 4 + 2 * kg + 1] = y1;
        }
    }
    __syncthreads();

    // ---- linear: 2-deep pipelined w-row loads + shfl reduce
    {
        const float4* hf = (const float4*)s_h3;
        const float4 h0v = hf[lane];
        const float4 h1v = hf[lane + 64];
        const float4* wr = (const float4*)(lin_w + (size_t)wv * 512);
        float4 w0 = wr[lane];
        float4 w1 = wr[lane + 64];
#pragma unroll 1
        for (int o = wv; o < 100; o += 8) {
            float4 nw0, nw1;
            const int on = o + 8;
            if (on < 100) {
                const float4* wn = (const float4*)(lin_w + (size_t)on * 512);
                nw0 = wn[lane];
                nw1 = wn[lane + 64];
            }
            float p = w0.x * h0v.x + w0.y * h0v.y + w0.z * h0v.z + w0.w * h0v.w
                    + w1.x * h1v.x + w1.y * h1v.y + w1.z * h1v.z + w1.w * h1v.w;
            p += __shfl_xor(p, 32);
            p += __shfl_xor(p, 16);
            p += __shfl_xor(p, 8);
            p += __shfl_xor(p, 4);
            p += __shfl_xor(p, 2);
            p += __shfl_xor(p, 1);
            if (lane == 0) out[(size_t)n * 100 + o] = p + lin_b[o];
            w0 = nw0;
            w1 = nw1;
        }
    }
}

extern "C" void kernel_launch(void* const* d_in, const int* in_sizes, int n_in,
                              void* d_out, int out_size, void* d_ws, size_t ws_size,
                              hipStream_t stream) {
    const float* x     = (const float*)d_in[0];
    const float* c1_bw = (const float*)d_in[1];
    const float* c1_sw = (const float*)d_in[2];
    const float* c1_sc = (const float*)d_in[3];
    const float* c2_bw = (const float*)d_in[4];
    const float* c2_sw = (const float*)d_in[5];
    const float* c2_sc = (const float*)d_in[6];
    const float* c3_bw = (const float*)d_in[7];
    const float* c3_sw = (const float*)d_in[8];
    const float* c3_sc = (const float*)d_in[9];
    const float* lin_w = (const float*)d_in[10];
    const float* lin_b = (const float*)d_in[11];
    float* out = (float*)d_out;

    float* ws = (float*)d_ws;
    float* h1 = ws;                      // 256*8*16*16 = 524288 floats
    uint4* w3g = (uint4*)(h1 + 524288);  // 4608 records = 73728 B

    // Kernel A: L1 [256,3,32,32] -> h1 [256,8,16,16]; + w3g prep (blocks 0-8).
    kan_l1<<<512, 512, 0, stream>>>(x, c1_bw, c1_sw, c1_sc,
                                    c3_bw, c3_sw, c3_sc, w3g, h1);
    // Kernel B: per-image L2 -> L3 -> linear. 256 blocks x 512.
    kan_l2l3lin<<<256, 512, 0, stream>>>(h1, c2_bw, c2_sw, c2_sc,
                                         w3g, lin_w, lin_b, out);
}